// Round 1
// baseline (544.992 us; speedup 1.0000x reference)
//
#include <hip/hip_runtime.h>

#define NBATCH   1000000
#define NBLOCKS  15625      // NBATCH / 64
#define EPB      64         // elements (= threads = 1 wave) per block

// 16B-aligned float4 (coalesced W chunks are provably 16B-aligned)
typedef float f4a __attribute__((ext_vector_type(4), aligned(16)));
// alignment-4 vector types for per-lane strided loads (HW allows dword-aligned
// multi-dword global loads on gfx950; compiler splits if it disagrees)
typedef float f4u __attribute__((ext_vector_type(4), aligned(4)));
typedef float f2u __attribute__((ext_vector_type(2), aligned(4)));

__global__ __launch_bounds__(EPB, 2) void
fused_grad_kernel(const float* __restrict__ R1g, const float* __restrict__ R2g,
                  const float* __restrict__ t1g, const float* __restrict__ t2g,
                  const float* __restrict__ f1g, const float* __restrict__ f2g,
                  const float* __restrict__ Wg,
                  float* __restrict__ out, float* __restrict__ partial) {
    // Single LDS buffer: W stage (20736 B = 64*81 floats), reused for outputs.
    // 20.7 KB/block -> 7 blocks/CU (was 5 at 27.4 KB with full LDS-DMA staging).
    __shared__ __align__(16) float sW[EPB * 81];

    const int lane = threadIdx.x;
    const int blk  = blockIdx.x;
    const size_t e0 = (size_t)blk * EPB;
    const size_t e  = e0 + lane;

    // ---- 1. issue coalesced W loads: this wave's 64 elements = 20736 B ----
    // wsrc is 16B-aligned (blk * 20736 B); chunk r, lane l -> +1024*r + 16*l B.
    // 1296 float4 chunks total: 20 full rounds + 16-lane partial round.
    const float* wsrc = Wg + e0 * 81;
    f4a c[21];
#pragma unroll
    for (int r = 0; r < 20; ++r)
        c[r] = *(const f4a*)(wsrc + 256 * r + 4 * lane);
    if (lane < 16)
        c[20] = *(const f4a*)(wsrc + 5120 + 4 * lane);

    // ---- 2. per-lane small-input loads (fly concurrently with W loads) ----
    float r1[9], r2[9];
    {
        f4u va = *(const f4u*)(R1g + e * 9);
        f4u vb = *(const f4u*)(R1g + e * 9 + 4);
        const float v8 = R1g[e * 9 + 8];
        r1[0] = va[0]; r1[1] = va[1]; r1[2] = va[2]; r1[3] = va[3];
        r1[4] = vb[0]; r1[5] = vb[1]; r1[6] = vb[2]; r1[7] = vb[3]; r1[8] = v8;
        f4u ua = *(const f4u*)(R2g + e * 9);
        f4u ub = *(const f4u*)(R2g + e * 9 + 4);
        const float u8 = R2g[e * 9 + 8];
        r2[0] = ua[0]; r2[1] = ua[1]; r2[2] = ua[2]; r2[3] = ua[3];
        r2[4] = ub[0]; r2[5] = ub[1]; r2[6] = ub[2]; r2[7] = ub[3]; r2[8] = u8;
    }
    f2u t1v = *(const f2u*)(t1g + e * 3);
    const float w1 = t1g[e * 3 + 2];
    f2u t2v = *(const f2u*)(t2g + e * 3);
    const float w2 = t2g[e * 3 + 2];
    const float x1 = t1v[0], y1 = t1v[1];
    const float x2 = t2v[0], y2 = t2v[1];
    const float a1 = f1g[e], a2 = f2g[e];

    // ---- 3. reg -> LDS (linear copy == element-major layout, b128 writes) ----
#pragma unroll
    for (int r = 0; r < 20; ++r)
        *(f4a*)(sW + 256 * r + 4 * lane) = c[r];
    if (lane < 16)
        *(f4a*)(sW + 5120 + 4 * lane) = c[20];

    // ---- 4. forward math (register-only, overlaps with LDS/VMEM drain) ----
    // R_rel = R2 @ R1^T
    float Rr[9];
#pragma unroll
    for (int i = 0; i < 3; ++i)
#pragma unroll
        for (int j = 0; j < 3; ++j)
            Rr[i * 3 + j] = r2[i * 3 + 0] * r1[j * 3 + 0]
                          + r2[i * 3 + 1] * r1[j * 3 + 1]
                          + r2[i * 3 + 2] * r1[j * 3 + 2];

    // E = Rr @ t1x - t2x @ Rr
    float E[9];
#pragma unroll
    for (int i = 0; i < 3; ++i) {
        E[i * 3 + 0] = Rr[i * 3 + 1] * w1 - Rr[i * 3 + 2] * y1;
        E[i * 3 + 1] = Rr[i * 3 + 2] * x1 - Rr[i * 3 + 0] * w1;
        E[i * 3 + 2] = Rr[i * 3 + 0] * y1 - Rr[i * 3 + 1] * x1;
    }
#pragma unroll
    for (int j = 0; j < 3; ++j) {
        E[0 * 3 + j] -= (y2 * Rr[2 * 3 + j] - w2 * Rr[1 * 3 + j]);
        E[1 * 3 + j] -= (w2 * Rr[0 * 3 + j] - x2 * Rr[2 * 3 + j]);
        E[2 * 3 + j] -= (x2 * Rr[1 * 3 + j] - y2 * Rr[0 * 3 + j]);
    }

    const float k1v[3] = {a1, a1, 1.0f};
    const float k2v[3] = {a2, a2, 1.0f};

    // F = k2[i] * E * k1[j]; normalize
    float Fh[9];
    float ss = 0.0f;
#pragma unroll
    for (int i = 0; i < 3; ++i)
#pragma unroll
        for (int j = 0; j < 3; ++j) {
            const float v = k2v[i] * E[i * 3 + j] * k1v[j];
            Fh[i * 3 + j] = v;
            ss += v * v;
        }
    const float nrm   = sqrtf(ss) + 1e-8f;
    const float inv_n = 1.0f / nrm;
#pragma unroll
    for (int k = 0; k < 9; ++k) Fh[k] *= inv_n;

    __syncthreads();   // transpose complete: all lanes' W rows visible

    // ---- 5. W_vec = W @ Fh  (stride-81 reads: odd stride -> conflict-free) ----
    float wv[9];
    const int wbase = lane * 81;
#pragma unroll
    for (int i = 0; i < 9; ++i) {
        float acc = 0.0f;
#pragma unroll
        for (int j = 0; j < 9; ++j) acc += sW[wbase + i * 9 + j] * Fh[j];
        wv[i] = acc;
    }

    float s2 = 0.0f;
#pragma unroll
    for (int k = 0; k < 9; ++k) s2 += Fh[k] * wv[k];

    // dF = (wv - s2*Fh)/n
    float dF[9];
#pragma unroll
    for (int k = 0; k < 9; ++k) dF[k] = (wv[k] - s2 * Fh[k]) * inv_n;

    // dE, d_f1, d_f2
    float dE[9];
    float df1 = 0.0f, df2 = 0.0f;
#pragma unroll
    for (int i = 0; i < 3; ++i)
#pragma unroll
        for (int j = 0; j < 3; ++j) {
            const float d  = dF[i * 3 + j];
            dE[i * 3 + j]  = d * k2v[i] * k1v[j];
            const float de = d * E[i * 3 + j];
            if (j < 2) df1 += de * k2v[i];
            if (i < 2) df2 += de * k1v[j];
        }

    // d_Rr = t2x @ dE - dE @ t1x
    float dRr[9];
#pragma unroll
    for (int i = 0; i < 3; ++i) {
        dRr[i * 3 + 0] = -(dE[i * 3 + 1] * w1 - dE[i * 3 + 2] * y1);
        dRr[i * 3 + 1] = -(dE[i * 3 + 2] * x1 - dE[i * 3 + 0] * w1);
        dRr[i * 3 + 2] = -(dE[i * 3 + 0] * y1 - dE[i * 3 + 1] * x1);
    }
#pragma unroll
    for (int j = 0; j < 3; ++j) {
        dRr[0 * 3 + j] += y2 * dE[2 * 3 + j] - w2 * dE[1 * 3 + j];
        dRr[1 * 3 + j] += w2 * dE[0 * 3 + j] - x2 * dE[2 * 3 + j];
        dRr[2 * 3 + j] += x2 * dE[1 * 3 + j] - y2 * dE[0 * 3 + j];
    }

    // d_t1 from d_t1x = Rr^T dE ; d_t2 from d_t2x = -dE Rr^T
    float dt1_0 = 0, dt1_1 = 0, dt1_2 = 0, dt2_0 = 0, dt2_1 = 0, dt2_2 = 0;
#pragma unroll
    for (int k = 0; k < 3; ++k) {
        dt1_0 += Rr[k * 3 + 2] * dE[k * 3 + 1] - Rr[k * 3 + 1] * dE[k * 3 + 2];
        dt1_1 += Rr[k * 3 + 0] * dE[k * 3 + 2] - Rr[k * 3 + 2] * dE[k * 3 + 0];
        dt1_2 += Rr[k * 3 + 1] * dE[k * 3 + 0] - Rr[k * 3 + 0] * dE[k * 3 + 1];
        dt2_0 += dE[1 * 3 + k] * Rr[2 * 3 + k] - dE[2 * 3 + k] * Rr[1 * 3 + k];
        dt2_1 += dE[2 * 3 + k] * Rr[0 * 3 + k] - dE[0 * 3 + k] * Rr[2 * 3 + k];
        dt2_2 += dE[0 * 3 + k] * Rr[1 * 3 + k] - dE[1 * 3 + k] * Rr[0 * 3 + k];
    }

    // d_R1 = dRr^T @ R2 ; d_R2 = dRr @ R1
    float dR1[9], dR2[9];
#pragma unroll
    for (int i = 0; i < 3; ++i)
#pragma unroll
        for (int j = 0; j < 3; ++j) {
            dR1[i * 3 + j] = dRr[0 * 3 + i] * r2[0 * 3 + j]
                           + dRr[1 * 3 + i] * r2[1 * 3 + j]
                           + dRr[2 * 3 + i] * r2[2 * 3 + j];
            dR2[i * 3 + j] = dRr[i * 3 + 0] * r1[0 * 3 + j]
                           + dRr[i * 3 + 1] * r1[1 * 3 + j]
                           + dRr[i * 3 + 2] * r1[2 * 3 + j];
        }

    // per-wave loss reduce -> one partial per block
    float lv = 0.5f * s2;
#pragma unroll
    for (int off = 32; off > 0; off >>= 1) lv += __shfl_down(lv, off, 64);
    if (lane == 0) partial[blk] = lv;

    // ---- 6. stage outputs in LDS (reuse sW), then coalesced dword stores ----
    __syncthreads();   // all lanes done reading sW
    float* sOut = sW;  // needs 1664 floats, sW has 5184
#pragma unroll
    for (int k = 0; k < 9; ++k) {
        sOut[lane * 9 + k]       = dR1[k];
        sOut[576 + lane * 9 + k] = dR2[k];
    }
    sOut[1152 + lane * 3 + 0] = dt1_0;
    sOut[1152 + lane * 3 + 1] = dt1_1;
    sOut[1152 + lane * 3 + 2] = dt1_2;
    sOut[1344 + lane * 3 + 0] = dt2_0;
    sOut[1344 + lane * 3 + 1] = dt2_1;
    sOut[1344 + lane * 3 + 2] = dt2_2;
    sOut[1536 + lane] = df1;
    sOut[1600 + lane] = df2;
    __syncthreads();

    const size_t Bc = NBATCH;
    float* oBase = out + 1;                 // out[0] is the loss scalar
    float* oR1 = oBase + e0 * 9;
    float* oR2 = oBase + Bc * 9  + e0 * 9;
    float* oT1 = oBase + Bc * 18 + e0 * 3;
    float* oT2 = oBase + Bc * 21 + e0 * 3;
    float* oF1 = oBase + Bc * 24 + e0;
    float* oF2 = oBase + Bc * 25 + e0;
#pragma unroll
    for (int it = 0; it < 9; ++it) {
        const int i = it * 64 + lane;
        oR1[i] = sOut[i];
        oR2[i] = sOut[576 + i];
    }
#pragma unroll
    for (int it = 0; it < 3; ++it) {
        const int i = it * 64 + lane;
        oT1[i] = sOut[1152 + i];
        oT2[i] = sOut[1344 + i];
    }
    oF1[lane] = sOut[1536 + lane];
    oF2[lane] = sOut[1600 + lane];
}

// reduce 15625 per-block partials (in double) -> out[0]
__global__ __launch_bounds__(256) void
finalize_kernel(const float* __restrict__ partial, float* __restrict__ out) {
    __shared__ double sd[256];
    double acc = 0.0;
    for (int i = threadIdx.x; i < NBLOCKS; i += 256) acc += (double)partial[i];
    sd[threadIdx.x] = acc;
    __syncthreads();
    for (int s = 128; s > 0; s >>= 1) {
        if (threadIdx.x < s) sd[threadIdx.x] += sd[threadIdx.x + s];
        __syncthreads();
    }
    if (threadIdx.x == 0) out[0] = (float)sd[0];
}

extern "C" void kernel_launch(void* const* d_in, const int* in_sizes, int n_in,
                              void* d_out, int out_size, void* d_ws, size_t ws_size,
                              hipStream_t stream) {
    const float* R1 = (const float*)d_in[0];
    const float* R2 = (const float*)d_in[1];
    const float* t1 = (const float*)d_in[2];
    const float* t2 = (const float*)d_in[3];
    const float* f1 = (const float*)d_in[4];
    const float* f2 = (const float*)d_in[5];
    const float* W  = (const float*)d_in[6];
    float* out     = (float*)d_out;
    float* partial = (float*)d_ws;   // NBLOCKS floats, fully rewritten each call

    fused_grad_kernel<<<NBLOCKS, EPB, 0, stream>>>(R1, R2, t1, t2, f1, f2, W,
                                                   out, partial);
    finalize_kernel<<<1, 256, 0, stream>>>(partial, out);
}

// Round 2
// 544.957 us; speedup vs baseline: 1.0001x; 1.0001x over previous
//
#include <hip/hip_runtime.h>

#define NBATCH   1000000
#define NBLOCKS  15625      // NBATCH / 64
#define EPB      64         // elements (= threads = 1 wave) per block

// 16B-aligned float4 (coalesced W chunks are provably 16B-aligned)
typedef float f4a __attribute__((ext_vector_type(4), aligned(16)));
// alignment-4 vector types for per-lane strided loads/stores (multi-dword
// global ops on gfx950 only require dword alignment; compiler handles it)
typedef float f4u __attribute__((ext_vector_type(4), aligned(4)));
typedef float f2u __attribute__((ext_vector_type(2), aligned(4)));

__global__ __launch_bounds__(EPB, 2) void
fused_grad_kernel(const float* __restrict__ R1g, const float* __restrict__ R2g,
                  const float* __restrict__ t1g, const float* __restrict__ t2g,
                  const float* __restrict__ f1g, const float* __restrict__ f2g,
                  const float* __restrict__ Wg,
                  float* __restrict__ out, float* __restrict__ partial) {
    // LDS: W transpose stage only (20736 B -> 7 blocks/CU). Outputs go
    // straight to global (per-lane strided stores cover each wave's output
    // region contiguously -> full-line L2 write combining, no staging needed).
    __shared__ __align__(16) float sW[EPB * 81];

    const int lane = threadIdx.x;
    const int blk  = blockIdx.x;
    const size_t e0 = (size_t)blk * EPB;
    const size_t e  = e0 + lane;

    // ---- 1. issue coalesced W loads: this wave's 64 elements = 20736 B ----
    // wsrc is 16B-aligned (blk * 20736 B); chunk r, lane l -> +1024*r + 16*l B.
    const float* wsrc = Wg + e0 * 81;
    f4a c[21];
#pragma unroll
    for (int r = 0; r < 20; ++r)
        c[r] = *(const f4a*)(wsrc + 256 * r + 4 * lane);
    if (lane < 16)
        c[20] = *(const f4a*)(wsrc + 5120 + 4 * lane);

    // ---- 2. per-lane small-input loads (fly concurrently with W loads) ----
    float r1[9], r2[9];
    {
        f4u va = *(const f4u*)(R1g + e * 9);
        f4u vb = *(const f4u*)(R1g + e * 9 + 4);
        const float v8 = R1g[e * 9 + 8];
        r1[0] = va[0]; r1[1] = va[1]; r1[2] = va[2]; r1[3] = va[3];
        r1[4] = vb[0]; r1[5] = vb[1]; r1[6] = vb[2]; r1[7] = vb[3]; r1[8] = v8;
        f4u ua = *(const f4u*)(R2g + e * 9);
        f4u ub = *(const f4u*)(R2g + e * 9 + 4);
        const float u8 = R2g[e * 9 + 8];
        r2[0] = ua[0]; r2[1] = ua[1]; r2[2] = ua[2]; r2[3] = ua[3];
        r2[4] = ub[0]; r2[5] = ub[1]; r2[6] = ub[2]; r2[7] = ub[3]; r2[8] = u8;
    }
    f2u t1v = *(const f2u*)(t1g + e * 3);
    const float w1 = t1g[e * 3 + 2];
    f2u t2v = *(const f2u*)(t2g + e * 3);
    const float w2 = t2g[e * 3 + 2];
    const float x1 = t1v[0], y1 = t1v[1];
    const float x2 = t2v[0], y2 = t2v[1];
    const float a1 = f1g[e], a2 = f2g[e];

    // ---- 3. reg -> LDS (linear copy == element-major layout, b128 writes) ----
#pragma unroll
    for (int r = 0; r < 20; ++r)
        *(f4a*)(sW + 256 * r + 4 * lane) = c[r];
    if (lane < 16)
        *(f4a*)(sW + 5120 + 4 * lane) = c[20];

    // ---- 4. forward math (register-only, overlaps with LDS/VMEM drain) ----
    // R_rel = R2 @ R1^T
    float Rr[9];
#pragma unroll
    for (int i = 0; i < 3; ++i)
#pragma unroll
        for (int j = 0; j < 3; ++j)
            Rr[i * 3 + j] = r2[i * 3 + 0] * r1[j * 3 + 0]
                          + r2[i * 3 + 1] * r1[j * 3 + 1]
                          + r2[i * 3 + 2] * r1[j * 3 + 2];

    // E = Rr @ t1x - t2x @ Rr
    float E[9];
#pragma unroll
    for (int i = 0; i < 3; ++i) {
        E[i * 3 + 0] = Rr[i * 3 + 1] * w1 - Rr[i * 3 + 2] * y1;
        E[i * 3 + 1] = Rr[i * 3 + 2] * x1 - Rr[i * 3 + 0] * w1;
        E[i * 3 + 2] = Rr[i * 3 + 0] * y1 - Rr[i * 3 + 1] * x1;
    }
#pragma unroll
    for (int j = 0; j < 3; ++j) {
        E[0 * 3 + j] -= (y2 * Rr[2 * 3 + j] - w2 * Rr[1 * 3 + j]);
        E[1 * 3 + j] -= (w2 * Rr[0 * 3 + j] - x2 * Rr[2 * 3 + j]);
        E[2 * 3 + j] -= (x2 * Rr[1 * 3 + j] - y2 * Rr[0 * 3 + j]);
    }

    const float k1v[3] = {a1, a1, 1.0f};
    const float k2v[3] = {a2, a2, 1.0f};

    // F = k2[i] * E * k1[j]; normalize
    float Fh[9];
    float ss = 0.0f;
#pragma unroll
    for (int i = 0; i < 3; ++i)
#pragma unroll
        for (int j = 0; j < 3; ++j) {
            const float v = k2v[i] * E[i * 3 + j] * k1v[j];
            Fh[i * 3 + j] = v;
            ss += v * v;
        }
    const float nrm   = sqrtf(ss) + 1e-8f;
    const float inv_n = 1.0f / nrm;
#pragma unroll
    for (int k = 0; k < 9; ++k) Fh[k] *= inv_n;

    __syncthreads();   // transpose complete: all lanes' W rows visible

    // ---- 5. W_vec = W @ Fh  (stride-81 reads: odd stride -> conflict-free) ----
    float wv[9];
    const int wbase = lane * 81;
#pragma unroll
    for (int i = 0; i < 9; ++i) {
        float acc = 0.0f;
#pragma unroll
        for (int j = 0; j < 9; ++j) acc += sW[wbase + i * 9 + j] * Fh[j];
        wv[i] = acc;
    }

    float s2 = 0.0f;
#pragma unroll
    for (int k = 0; k < 9; ++k) s2 += Fh[k] * wv[k];

    // dF = (wv - s2*Fh)/n
    float dF[9];
#pragma unroll
    for (int k = 0; k < 9; ++k) dF[k] = (wv[k] - s2 * Fh[k]) * inv_n;

    // dE, d_f1, d_f2
    float dE[9];
    float df1 = 0.0f, df2 = 0.0f;
#pragma unroll
    for (int i = 0; i < 3; ++i)
#pragma unroll
        for (int j = 0; j < 3; ++j) {
            const float d  = dF[i * 3 + j];
            dE[i * 3 + j]  = d * k2v[i] * k1v[j];
            const float de = d * E[i * 3 + j];
            if (j < 2) df1 += de * k2v[i];
            if (i < 2) df2 += de * k1v[j];
        }

    // d_Rr = t2x @ dE - dE @ t1x
    float dRr[9];
#pragma unroll
    for (int i = 0; i < 3; ++i) {
        dRr[i * 3 + 0] = -(dE[i * 3 + 1] * w1 - dE[i * 3 + 2] * y1);
        dRr[i * 3 + 1] = -(dE[i * 3 + 2] * x1 - dE[i * 3 + 0] * w1);
        dRr[i * 3 + 2] = -(dE[i * 3 + 0] * y1 - dE[i * 3 + 1] * x1);
    }
#pragma unroll
    for (int j = 0; j < 3; ++j) {
        dRr[0 * 3 + j] += y2 * dE[2 * 3 + j] - w2 * dE[1 * 3 + j];
        dRr[1 * 3 + j] += w2 * dE[0 * 3 + j] - x2 * dE[2 * 3 + j];
        dRr[2 * 3 + j] += x2 * dE[1 * 3 + j] - y2 * dE[0 * 3 + j];
    }

    // d_t1 from d_t1x = Rr^T dE ; d_t2 from d_t2x = -dE Rr^T
    float dt1_0 = 0, dt1_1 = 0, dt1_2 = 0, dt2_0 = 0, dt2_1 = 0, dt2_2 = 0;
#pragma unroll
    for (int k = 0; k < 3; ++k) {
        dt1_0 += Rr[k * 3 + 2] * dE[k * 3 + 1] - Rr[k * 3 + 1] * dE[k * 3 + 2];
        dt1_1 += Rr[k * 3 + 0] * dE[k * 3 + 2] - Rr[k * 3 + 2] * dE[k * 3 + 0];
        dt1_2 += Rr[k * 3 + 1] * dE[k * 3 + 0] - Rr[k * 3 + 0] * dE[k * 3 + 1];
        dt2_0 += dE[1 * 3 + k] * Rr[2 * 3 + k] - dE[2 * 3 + k] * Rr[1 * 3 + k];
        dt2_1 += dE[2 * 3 + k] * Rr[0 * 3 + k] - dE[0 * 3 + k] * Rr[2 * 3 + k];
        dt2_2 += dE[0 * 3 + k] * Rr[1 * 3 + k] - dE[1 * 3 + k] * Rr[0 * 3 + k];
    }

    // d_R1 = dRr^T @ R2 ; d_R2 = dRr @ R1
    float dR1[9], dR2[9];
#pragma unroll
    for (int i = 0; i < 3; ++i)
#pragma unroll
        for (int j = 0; j < 3; ++j) {
            dR1[i * 3 + j] = dRr[0 * 3 + i] * r2[0 * 3 + j]
                           + dRr[1 * 3 + i] * r2[1 * 3 + j]
                           + dRr[2 * 3 + i] * r2[2 * 3 + j];
            dR2[i * 3 + j] = dRr[i * 3 + 0] * r1[0 * 3 + j]
                           + dRr[i * 3 + 1] * r1[1 * 3 + j]
                           + dRr[i * 3 + 2] * r1[2 * 3 + j];
        }

    // per-wave loss reduce -> one partial per block
    float lv = 0.5f * s2;
#pragma unroll
    for (int off = 32; off > 0; off >>= 1) lv += __shfl_down(lv, off, 64);
    if (lane == 0) partial[blk] = lv;

    // ---- 6. direct per-lane stores (no LDS staging, no barriers) ----
    // Each wave's 64 lanes cover the 2304 B (R), 768 B (t), 256 B (f) output
    // regions contiguously and completely -> full-line write combining in L2.
    const size_t Bc = NBATCH;
    float* oBase = out + 1;                 // out[0] is the loss scalar
    float* oR1 = oBase + e * 9;
    float* oR2 = oBase + Bc * 9  + e * 9;
    float* oT1 = oBase + Bc * 18 + e * 3;
    float* oT2 = oBase + Bc * 21 + e * 3;
    float* oF1 = oBase + Bc * 24 + e;
    float* oF2 = oBase + Bc * 25 + e;

    f4u s0, s1;
    s0[0] = dR1[0]; s0[1] = dR1[1]; s0[2] = dR1[2]; s0[3] = dR1[3];
    s1[0] = dR1[4]; s1[1] = dR1[5]; s1[2] = dR1[6]; s1[3] = dR1[7];
    *(f4u*)(oR1)     = s0;
    *(f4u*)(oR1 + 4) = s1;
    oR1[8] = dR1[8];
    s0[0] = dR2[0]; s0[1] = dR2[1]; s0[2] = dR2[2]; s0[3] = dR2[3];
    s1[0] = dR2[4]; s1[1] = dR2[5]; s1[2] = dR2[6]; s1[3] = dR2[7];
    *(f4u*)(oR2)     = s0;
    *(f4u*)(oR2 + 4) = s1;
    oR2[8] = dR2[8];

    f2u tv;
    tv[0] = dt1_0; tv[1] = dt1_1;
    *(f2u*)(oT1) = tv;
    oT1[2] = dt1_2;
    tv[0] = dt2_0; tv[1] = dt2_1;
    *(f2u*)(oT2) = tv;
    oT2[2] = dt2_2;

    oF1[0] = df1;
    oF2[0] = df2;
}

// reduce 15625 per-block partials (in double) -> out[0]
__global__ __launch_bounds__(256) void
finalize_kernel(const float* __restrict__ partial, float* __restrict__ out) {
    __shared__ double sd[256];
    double acc = 0.0;
    for (int i = threadIdx.x; i < NBLOCKS; i += 256) acc += (double)partial[i];
    sd[threadIdx.x] = acc;
    __syncthreads();
    for (int s = 128; s > 0; s >>= 1) {
        if (threadIdx.x < s) sd[threadIdx.x] += sd[threadIdx.x + s];
        __syncthreads();
    }
    if (threadIdx.x == 0) out[0] = (float)sd[0];
}

extern "C" void kernel_launch(void* const* d_in, const int* in_sizes, int n_in,
                              void* d_out, int out_size, void* d_ws, size_t ws_size,
                              hipStream_t stream) {
    const float* R1 = (const float*)d_in[0];
    const float* R2 = (const float*)d_in[1];
    const float* t1 = (const float*)d_in[2];
    const float* t2 = (const float*)d_in[3];
    const float* f1 = (const float*)d_in[4];
    const float* f2 = (const float*)d_in[5];
    const float* W  = (const float*)d_in[6];
    float* out     = (float*)d_out;
    float* partial = (float*)d_ws;   // NBLOCKS floats, fully rewritten each call

    fused_grad_kernel<<<NBLOCKS, EPB, 0, stream>>>(R1, R2, t1, t2, f1, f2, W,
                                                   out, partial);
    finalize_kernel<<<1, 256, 0, stream>>>(partial, out);
}